// Round 3
// baseline (1682.573 us; speedup 1.0000x reference)
//
#include <hip/hip_runtime.h>
#include <math.h>

#define NWAVES 8
#define BS (NWAVES * 64)
#define NBLK 512

// LDS-pipe-minimal design:
//  - x[b] is wave-uniform -> scalar (s_load) broadcasts via readfirstlane'd pointer
//  - weights in LDS, row-major per output-feature row, XOR-swizzled, ds_read_b128
//  - ALL wave reductions via DPP row_shr/row_bcast (VALU pipe) + v_readlane; zero ds_swizzle
//  - per-wave stage-2 scratch in LDS (broadcast reads only)
// One wave per batch element. Stage1: lane = f (64). Stage2: lanes 0-31 = ya cols,
// lanes 32-63 = yn cols. Softmax over dim=1 (normalize over i for fixed j).

template <int CTRL, int RMASK>
__device__ __forceinline__ float dpp_term(float v) {
  return __int_as_float(__builtin_amdgcn_update_dpp(0, __float_as_int(v), CTRL, RMASK, 0xf, true));
}

// full wave64 sum, result broadcast (uniform)
__device__ __forceinline__ float wave_sum_bcast(float v) {
  v += dpp_term<0x111, 0xf>(v);  // row_shr:1
  v += dpp_term<0x112, 0xf>(v);  // row_shr:2
  v += dpp_term<0x114, 0xf>(v);  // row_shr:4
  v += dpp_term<0x118, 0xf>(v);  // row_shr:8
  v += dpp_term<0x142, 0xa>(v);  // row_bcast:15 -> rows 1,3
  v += dpp_term<0x143, 0xc>(v);  // row_bcast:31 -> rows 2,3
  return __int_as_float(__builtin_amdgcn_readlane(__float_as_int(v), 63));
}

// per-32-lane-half sums: lo = sum lanes 0..31, hi = sum lanes 32..63 (both uniform)
__device__ __forceinline__ void half_sum2(float v, float& lo, float& hi) {
  v += dpp_term<0x111, 0xf>(v);
  v += dpp_term<0x112, 0xf>(v);
  v += dpp_term<0x114, 0xf>(v);
  v += dpp_term<0x118, 0xf>(v);
  v += dpp_term<0x142, 0xa>(v);  // lane31 = rows0+1, lane63 = rows2+3
  lo = __int_as_float(__builtin_amdgcn_readlane(__float_as_int(v), 31));
  hi = __int_as_float(__builtin_amdgcn_readlane(__float_as_int(v), 63));
}

__device__ __forceinline__ void attn_bn(const float* s, const float* t, const float* h,
                                        const float* bns, const float* bnt, float* o) {
  float acc[5] = {0.f, 0.f, 0.f, 0.f, 0.f};
#pragma unroll
  for (int j = 0; j < 5; ++j) {
    float col[5];
    float mx = -1e30f;
#pragma unroll
    for (int i = 0; i < 5; ++i) {
      float e = s[i] + t[j];
      e = (e > 0.f) ? e : 0.2f * e;  // LeakyReLU(0.2)
      col[i] = e;
      mx = fmaxf(mx, e);
    }
    float sum = 0.f;
#pragma unroll
    for (int i = 0; i < 5; ++i) {
      col[i] = __expf(col[i] - mx);
      sum += col[i];
    }
    float hj = h[j] / sum;
#pragma unroll
    for (int i = 0; i < 5; ++i) acc[i] += col[i] * hj;
  }
#pragma unroll
  for (int i = 0; i < 5; ++i) o[i] = fmaxf(acc[i] * bns[i] + bnt[i], 0.f);
}

__global__ __launch_bounds__(BS, 4) void gat_fused(
    const float* __restrict__ x,
    const float* __restrict__ Wt1, const float* __restrict__ a11, const float* __restrict__ a21,
    const float* __restrict__ g1, const float* __restrict__ b1,
    const float* __restrict__ m1, const float* __restrict__ v1,
    const float* __restrict__ Wt2, const float* __restrict__ a12, const float* __restrict__ a22,
    const float* __restrict__ g2, const float* __restrict__ b2,
    const float* __restrict__ m2, const float* __restrict__ v2,
    const float* __restrict__ Wl, const float* __restrict__ bl,
    float* __restrict__ out, int B) {
  __shared__ float s_w1[64 * 128];        // [f][k-chunk swizzled]: w1[f][k] at f*128+((k>>2)^(f&7))*4+(k&3)
  __shared__ float s_w2[32 * 64];         // same scheme, 16 chunks/row
  __shared__ float s_xp[NWAVES][5 * 128]; // per-wave: [i][0..63]=xa1, [i][64..127]=xn1

  const int tid = threadIdx.x;
  const int lane = tid & 63;

  // ---- one-time swizzled weight staging ----
  for (int t = tid; t < 64 * 125; t += BS) {
    int f = t / 125, k = t - f * 125;
    s_w1[f * 128 + (((k >> 2) ^ (f & 7)) << 2) + (k & 3)] = Wt1[t];
  }
  for (int t = tid; t < 32 * 64; t += BS) {
    int f = t >> 6, k = t & 63;
    s_w2[f * 64 + (((k >> 2) ^ (f & 7)) << 2) + (k & 3)] = Wt2[t];
  }
  __syncthreads();

  const int wv = __builtin_amdgcn_readfirstlane(tid >> 6);
  const int f2 = lane & 31;
  const int half = lane >> 5;

  const float va11 = a11[lane], va21 = a21[lane];
  const float va12 = a12[f2], va22 = a22[f2];

  float bn1s[5], bn1t[5], bn2s[5], bn2t[5], blv[13];
#pragma unroll
  for (int i = 0; i < 5; ++i) {
    float s1 = g1[i] * rsqrtf(v1[i] + 1e-5f);
    bn1s[i] = s1; bn1t[i] = b1[i] - m1[i] * s1;
    float s2 = g2[i] * rsqrtf(v2[i] + 1e-5f);
    bn2s[i] = s2; bn2t[i] = b2[i] - m2[i] * s2;
  }
#pragma unroll
  for (int o = 0; o < 13; ++o) blv[o] = bl[o];

  const float* wl = Wl + lane;  // Wl[o][i*64+lane] = wl[o*320 + i*64]
  const int sw1 = lane & 7;

  const int b0 = (int)blockIdx.x * NWAVES + wv;
  const int bstep = NBLK * NWAVES;

  for (int b = b0; b < B; b += bstep) {
    const int bu = __builtin_amdgcn_readfirstlane(b);
    const float* xb = x + (size_t)bu * 1250;  // uniform pointer -> s_load broadcasts

    // ---- stage-1 GEMM: hA[i][lane], hN[i][lane];  k = 0..124 ----
    float hA[5] = {0, 0, 0, 0, 0}, hN[5] = {0, 0, 0, 0, 0};
#pragma unroll
    for (int c = 0; c < 31; ++c) {  // k = 4c..4c+3
      const float4 w4 = *reinterpret_cast<const float4*>(&s_w1[lane * 128 + ((c ^ sw1) << 2)]);
#pragma unroll
      for (int i = 0; i < 5; ++i) {
        const float* xr = xb + i * 250 + 4 * c;
        hA[i] = fmaf(xr[0], w4.x, fmaf(xr[1], w4.y, fmaf(xr[2], w4.z, fmaf(xr[3], w4.w, hA[i]))));
        hN[i] = fmaf(xr[125], w4.x, fmaf(xr[126], w4.y, fmaf(xr[127], w4.z, fmaf(xr[128], w4.w, hN[i]))));
      }
    }
    {  // tail k = 124
      const float w124 = s_w1[lane * 128 + ((31 ^ sw1) << 2)];
#pragma unroll
      for (int i = 0; i < 5; ++i) {
        hA[i] = fmaf(xb[i * 250 + 124], w124, hA[i]);
        hN[i] = fmaf(xb[i * 250 + 249], w124, hN[i]);
      }
    }

    // ---- stage-1 scores via DPP wave sums (uniform results) ----
    float sA[5], tA[5], sN[5], tN[5];
#pragma unroll
    for (int i = 0; i < 5; ++i) {
      sA[i] = wave_sum_bcast(hA[i] * va11);
      tA[i] = wave_sum_bcast(hA[i] * va21);
      sN[i] = wave_sum_bcast(hN[i] * va11);
      tN[i] = wave_sum_bcast(hN[i] * va21);
    }

    float xa1[5], xn1[5];
    attn_bn(sA, tA, hA, bn1s, bn1t, xa1);
    attn_bn(sN, tN, hN, bn1s, bn1t, xn1);

    // ---- publish stage-1 outputs (wave-private LDS, no barrier) ----
#pragma unroll
    for (int i = 0; i < 5; ++i) {
      s_xp[wv][i * 128 + lane] = xa1[i];
      s_xp[wv][i * 128 + 64 + lane] = xn1[i];
    }

    // ---- stage-2 GEMM: lanes 0..31 -> gA=xa1@W2, 32..63 -> gN=xn1@W2 ----
    float g[5] = {0, 0, 0, 0, 0};
    const float* sxp = &s_xp[wv][half * 64];
    const int sw2 = f2 & 7;
#pragma unroll
    for (int c = 0; c < 16; ++c) {
      const float4 w4 = *reinterpret_cast<const float4*>(&s_w2[f2 * 64 + ((c ^ sw2) << 2)]);
#pragma unroll
      for (int i = 0; i < 5; ++i) {
        const float4 p4 = *reinterpret_cast<const float4*>(&sxp[i * 128 + 4 * c]);
        g[i] += p4.x * w4.x + p4.y * w4.y + p4.z * w4.z + p4.w * w4.w;
      }
    }

    // ---- stage-2 scores: per-half sums; ya uses (gA.a12, gN.a22), yn uses (gN.a12, gA.a22) ----
    float su[5], tv[5];
#pragma unroll
    for (int i = 0; i < 5; ++i) {
      float ulo, uhi, vlo, vhi;
      half_sum2(g[i] * va12, ulo, uhi);
      half_sum2(g[i] * va22, vlo, vhi);
      su[i] = half ? uhi : ulo;
      tv[i] = half ? vlo : vhi;
    }

    float z[5];
    attn_bn(su, tv, g, bn2s, bn2t, z);  // z[i] = (half?yn:ya)[i][f2] = feat[i*64+lane]

    // ---- final Linear(320,13) via DPP wave sums ----
    float ov = 0.f;
#pragma unroll
    for (int o = 0; o < 13; ++o) {
      float p = 0.f;
#pragma unroll
      for (int i = 0; i < 5; ++i) p = fmaf(z[i], wl[o * 320 + i * 64], p);
      float ro = wave_sum_bcast(p) + blv[o];
      ov = (lane == o) ? ro : ov;
    }
    if (lane < 13) out[(size_t)bu * 13 + lane] = ov;
  }
}

extern "C" void kernel_launch(void* const* d_in, const int* in_sizes, int n_in,
                              void* d_out, int out_size, void* d_ws, size_t ws_size,
                              hipStream_t stream) {
  (void)n_in; (void)out_size; (void)d_ws; (void)ws_size;
  const float* x   = (const float*)d_in[0];
  const float* Wt1 = (const float*)d_in[1];
  const float* a11 = (const float*)d_in[2];
  const float* a21 = (const float*)d_in[3];
  const float* g1  = (const float*)d_in[4];
  const float* b1  = (const float*)d_in[5];
  const float* m1  = (const float*)d_in[6];
  const float* v1  = (const float*)d_in[7];
  const float* Wt2 = (const float*)d_in[8];
  const float* a12 = (const float*)d_in[9];
  const float* a22 = (const float*)d_in[10];
  const float* g2  = (const float*)d_in[11];
  const float* b2  = (const float*)d_in[12];
  const float* m2  = (const float*)d_in[13];
  const float* v2  = (const float*)d_in[14];
  const float* Wl  = (const float*)d_in[15];
  const float* bl  = (const float*)d_in[16];
  float* out = (float*)d_out;

  int B = in_sizes[0] / 1250;

  hipLaunchKernelGGL(gat_fused, dim3(NBLK), dim3(BS), 0, stream,
                     x, Wt1, a11, a21, g1, b1, m1, v1,
                     Wt2, a12, a22, g2, b2, m2, v2, Wl, bl, out, B);
}

// Round 4
// 600.811 us; speedup vs baseline: 2.8005x; 2.8005x over previous
//
#include <hip/hip_runtime.h>
#include <math.h>

// Fused GAT via f16 MFMA (fp32 accumulate).
// Block = 256 thr (4 waves). Wave w: group g=w>>1 (16 b's), half hf=w&1 (0=A,1=N).
// Stage-1 GEMM: M-tile = 16 b's of row (i,hf); A-frags loaded per-lane direct from
// global x (f32->f16), B-frags = W1 pre-swizzled f16 in LDS. C-frag: col(f)=l&15,
// row(b)=4*(l>>4)+reg  ->  attention score reduce = DPP allreduce over 16 lanes,
// softmax+PV+BN lane-local. xa1/xn1 -> swizzled f16 LDS tiles -> stage-2 MFMA
// (both gA,gN per wave), attention-2, final Linear partials + cross-wave combine.

typedef float f32x4 __attribute__((ext_vector_type(4)));
typedef _Float16 f16x8 __attribute__((ext_vector_type(8)));

#define NBLKS 512
#define BSZ 256

template <int C>
__device__ __forceinline__ float dppmov(float v) {
  return __int_as_float(__builtin_amdgcn_update_dpp(0, __float_as_int(v), C, 0xf, 0xf, true));
}
// allreduce-sum over each 16-lane group (cols of one C-frag row-group)
__device__ __forceinline__ float red16(float v) {
  v += dppmov<0xB1>(v);   // quad_perm xor1
  v += dppmov<0x4E>(v);   // quad_perm xor2
  v += dppmov<0x141>(v);  // row_half_mirror (crosses 4-boundary)
  v += dppmov<0x140>(v);  // row_mirror (crosses 8-boundary)
  return v;
}

__global__ __launch_bounds__(BSZ, 2) void gat_mfma(
    const float* __restrict__ x,
    const float* __restrict__ Wt1, const float* __restrict__ a11, const float* __restrict__ a21,
    const float* __restrict__ g1, const float* __restrict__ b1,
    const float* __restrict__ m1, const float* __restrict__ v1,
    const float* __restrict__ Wt2, const float* __restrict__ a12, const float* __restrict__ a22,
    const float* __restrict__ g2, const float* __restrict__ b2,
    const float* __restrict__ m2, const float* __restrict__ v2,
    const float* __restrict__ Wl, const float* __restrict__ bl,
    float* __restrict__ out, int B) {
  __shared__ alignas(16) _Float16 lW1[64 * 128];          // [f][k-swizzled], k pad 128 w/ 0
  __shared__ alignas(16) _Float16 lW2[32 * 64];           // [f2][k-swizzled]
  __shared__ alignas(16) _Float16 lXA[2 * 2 * 5 * 1024];  // [g][hf][i][16b x 64f swizzled]
  __shared__ float lWl[13 * 320];
  __shared__ float lP[2][16][16];  // [g][b][o] partial from odd wave

  const int tid = threadIdx.x;
  const int l = tid & 63;
  const int w = tid >> 6;
  const int g = w >> 1;
  const int hf = w & 1;
  const int l15 = l & 15;
  const int cg = l >> 4;  // 0..3: k-group (frags) / row-group (C)

  // ---- one-time staging: W1, W2 (f16, chunk-swizzled), Wl ----
  for (int t = tid; t < 64 * 128; t += BSZ) {
    int f = t >> 7, k = t & 127;
    float vv = (k < 125) ? Wt1[f * 125 + k] : 0.f;
    lW1[f * 128 + (((k >> 3) ^ (f & 7)) << 3) + (k & 7)] = (_Float16)vv;
  }
  for (int t = tid; t < 32 * 64; t += BSZ) {
    int f = t >> 6, k = t & 63;
    lW2[f * 64 + (((k >> 3) ^ (f & 7)) << 3) + (k & 7)] = (_Float16)Wt2[t];
  }
  for (int t = tid; t < 13 * 320; t += BSZ) lWl[t] = Wl[t];

  // per-lane attention vectors
  float a1v[4], a2v[4];
#pragma unroll
  for (int nt = 0; nt < 4; ++nt) { a1v[nt] = a11[nt * 16 + l15]; a2v[nt] = a21[nt * 16 + l15]; }
  float a12v[2], a22v[2];
#pragma unroll
  for (int nt = 0; nt < 2; ++nt) { a12v[nt] = a12[nt * 16 + l15]; a22v[nt] = a22[nt * 16 + l15]; }
  // BN folded (uniform -> scalar regs)
  float bns1[5], bnt1[5], bns2[5], bnt2[5];
#pragma unroll
  for (int i = 0; i < 5; ++i) {
    float s1 = g1[i] * rsqrtf(v1[i] + 1e-5f);
    bns1[i] = s1; bnt1[i] = b1[i] - m1[i] * s1;
    float s2 = g2[i] * rsqrtf(v2[i] + 1e-5f);
    bns2[i] = s2; bnt2[i] = b2[i] - m2[i] * s2;
  }
  const float blv = (l15 < 13) ? bl[l15] : 0.f;
  __syncthreads();

  const int iters = (B + NBLKS * 32 - 1) / (NBLKS * 32);
  for (int it = 0; it < iters; ++it) {
    const int b0 = (it * NBLKS + (int)blockIdx.x) * 32;
    if (b0 >= B) break;
    const int bb = b0 + g * 16;  // this wave-pair's 16 b's

    // ================= stage 1 =================
    const float* xb0 = x + (size_t)(bb + l15) * 1250 + hf * 125;
    const float* xb0s = (cg == 3) ? xb0 - 32 : xb0;  // OOB-safe tail (W1 pad=0 kills value)

    f32x4 acc[5][4] = {};  // [i][nt]
#pragma unroll
    for (int kt = 0; kt < 4; ++kt) {
      float v[5][8];
#pragma unroll
      for (int i = 0; i < 5; ++i) {
        const float* r0 = xb0 + i * 250 + kt * 32 + cg * 8;
        const float* rs = xb0s + i * 250 + 96 + cg * 8;
#pragma unroll
        for (int t = 0; t < 8; ++t) v[i][t] = (kt == 3 && t >= 5) ? rs[t] : r0[t];
      }
      f16x8 af[5];
#pragma unroll
      for (int i = 0; i < 5; ++i)
#pragma unroll
        for (int t = 0; t < 8; ++t) af[i][t] = (_Float16)v[i][t];
#pragma unroll
      for (int nt = 0; nt < 4; ++nt) {
        int f = nt * 16 + l15;
        f16x8 bf = *(const f16x8*)&lW1[f * 128 + (((kt * 4 + cg) ^ (f & 7)) << 3)];
#pragma unroll
        for (int i = 0; i < 5; ++i)
          acc[i][nt] = __builtin_amdgcn_mfma_f32_16x16x32_f16(af[i], bf, acc[i][nt], 0, 0, 0);
      }
    }

    // scores: S1/T1[i][r] for b-row = 4*cg + r (uniform within 16-lane group)
    float S1[5][4], T1[5][4];
#pragma unroll
    for (int i = 0; i < 5; ++i)
#pragma unroll
      for (int r = 0; r < 4; ++r) {
        float ps = acc[i][0][r] * a1v[0] + acc[i][1][r] * a1v[1] +
                   acc[i][2][r] * a1v[2] + acc[i][3][r] * a1v[3];
        S1[i][r] = red16(ps);
        float pt = acc[i][0][r] * a2v[0] + acc[i][1][r] * a2v[1] +
                   acc[i][2][r] * a2v[2] + acc[i][3][r] * a2v[3];
        T1[i][r] = red16(pt);
      }

    // softmax(dim=i) + PV + BN1 + ReLU -> f16 LDS tiles
    const int tbase = ((g * 2 + hf) * 5) * 1024;
#pragma unroll
    for (int r = 0; r < 4; ++r) {
      const int brow = 4 * cg + r, b7 = brow & 7;
      float att[5][5];
#pragma unroll
      for (int j = 0; j < 5; ++j) {
        float ex[5], sum = 0.f;
#pragma unroll
        for (int i2 = 0; i2 < 5; ++i2) {
          float e = S1[i2][r] + T1[j][r];
          e = (e > 0.f) ? e : 0.2f * e;
          ex[i2] = __expf(e);
          sum += ex[i2];
        }
        float inv = __builtin_amdgcn_rcpf(sum);
#pragma unroll
        for (int i2 = 0; i2 < 5; ++i2) att[i2][j] = ex[i2] * inv;
      }
#pragma unroll
      for (int nt = 0; nt < 4; ++nt) {
        float h0 = acc[0][nt][r], h1v = acc[1][nt][r], h2v = acc[2][nt][r],
              h3 = acc[3][nt][r], h4 = acc[4][nt][r];
        const int fc = nt * 16 + l15;
        const int el = brow * 64 + ((((fc >> 3) ^ b7)) << 3) + (fc & 7);
#pragma unroll
        for (int i2 = 0; i2 < 5; ++i2) {
          float o = att[i2][0] * h0 + att[i2][1] * h1v + att[i2][2] * h2v +
                    att[i2][3] * h3 + att[i2][4] * h4;
          o = fmaxf(o * bns1[i2] + bnt1[i2], 0.f);
          lXA[tbase + i2 * 1024 + el] = (_Float16)o;
        }
      }
    }
    __syncthreads();

    // ================= stage 2 =================
    f32x4 gacc[2][5][2] = {};  // [src: 0=gA,1=gN][i][nt]
#pragma unroll
    for (int src = 0; src < 2; ++src) {
      const int abase = ((g * 2 + src) * 5) * 1024;
#pragma unroll
      for (int kt = 0; kt < 2; ++kt) {
        const int ch = kt * 4 + cg;
        f16x8 bf0 = *(const f16x8*)&lW2[(0 * 16 + l15) * 64 + ((ch ^ (l15 & 7)) << 3)];
        f16x8 bf1 = *(const f16x8*)&lW2[(1 * 16 + l15) * 64 + ((ch ^ (l15 & 7)) << 3)];
#pragma unroll
        for (int i = 0; i < 5; ++i) {
          f16x8 af = *(const f16x8*)&lXA[abase + i * 1024 + l15 * 64 + ((ch ^ (l15 & 7)) << 3)];
          gacc[src][i][0] = __builtin_amdgcn_mfma_f32_16x16x32_f16(af, bf0, gacc[src][i][0], 0, 0, 0);
          gacc[src][i][1] = __builtin_amdgcn_mfma_f32_16x16x32_f16(af, bf1, gacc[src][i][1], 0, 0, 0);
        }
      }
    }

    // scores-2: h1 = gacc[hf] (own path), h2 = gacc[1-hf]
    float S2[5][4], T2[5][4];
#pragma unroll
    for (int i = 0; i < 5; ++i)
#pragma unroll
      for (int r = 0; r < 4; ++r) {
        S2[i][r] = red16(gacc[hf][i][0][r] * a12v[0] + gacc[hf][i][1][r] * a12v[1]);
        T2[i][r] = red16(gacc[1 ^ hf][i][0][r] * a22v[0] + gacc[1 ^ hf][i][1][r] * a22v[1]);
      }

    // softmax-2 + PV + BN2 + ReLU, in-place into gacc[hf]
#pragma unroll
    for (int r = 0; r < 4; ++r) {
      float att[5][5];
#pragma unroll
      for (int j = 0; j < 5; ++j) {
        float ex[5], sum = 0.f;
#pragma unroll
        for (int i2 = 0; i2 < 5; ++i2) {
          float e = S2[i2][r] + T2[j][r];
          e = (e > 0.f) ? e : 0.2f * e;
          ex[i2] = __expf(e);
          sum += ex[i2];
        }
        float inv = __builtin_amdgcn_rcpf(sum);
#pragma unroll
        for (int i2 = 0; i2 < 5; ++i2) att[i2][j] = ex[i2] * inv;
      }
#pragma unroll
      for (int nt = 0; nt < 2; ++nt) {
        float h0 = gacc[hf][0][nt][r], h1v = gacc[hf][1][nt][r], h2v = gacc[hf][2][nt][r],
              h3 = gacc[hf][3][nt][r], h4 = gacc[hf][4][nt][r];
#pragma unroll
        for (int i2 = 0; i2 < 5; ++i2) {
          float o = att[i2][0] * h0 + att[i2][1] * h1v + att[i2][2] * h2v +
                    att[i2][3] * h3 + att[i2][4] * h4;
          gacc[hf][i2][nt][r] = fmaxf(o * bns2[i2] + bnt2[i2], 0.f);
        }
      }
    }

    // final Linear(320,13): this wave covers cols c = i*64 + hf*32 + nt*16 + l15
    float ovs[4] = {0.f, 0.f, 0.f, 0.f};
#pragma unroll
    for (int o = 0; o < 13; ++o) {
      float wv[10];
#pragma unroll
      for (int i = 0; i < 5; ++i)
#pragma unroll
        for (int nt = 0; nt < 2; ++nt)
          wv[i * 2 + nt] = lWl[o * 320 + i * 64 + hf * 32 + nt * 16 + l15];
#pragma unroll
      for (int r = 0; r < 4; ++r) {
        float p = 0.f;
#pragma unroll
        for (int i = 0; i < 5; ++i)
#pragma unroll
          for (int nt = 0; nt < 2; ++nt)
            p = fmaf(gacc[hf][i][nt][r], wv[i * 2 + nt], p);
        p = red16(p);
        ovs[r] = (l15 == o) ? p : ovs[r];
      }
    }

    if (hf == 1) {
#pragma unroll
      for (int r = 0; r < 4; ++r)
        if (l15 < 13) lP[g][4 * cg + r][l15] = ovs[r];
    }
    __syncthreads();
    if (hf == 0) {
#pragma unroll
      for (int r = 0; r < 4; ++r) {
        const int brow = 4 * cg + r;
        float val = ovs[r] + lP[g][brow][l15] + blv;
        if (l15 < 13) out[(size_t)(bb + brow) * 13 + l15] = val;
      }
    }
  }
}

extern "C" void kernel_launch(void* const* d_in, const int* in_sizes, int n_in,
                              void* d_out, int out_size, void* d_ws, size_t ws_size,
                              hipStream_t stream) {
  (void)n_in; (void)out_size; (void)d_ws; (void)ws_size;
  const float* x   = (const float*)d_in[0];
  const float* Wt1 = (const float*)d_in[1];
  const float* a11 = (const float*)d_in[2];
  const float* a21 = (const float*)d_in[3];
  const float* g1  = (const float*)d_in[4];
  const float* b1  = (const float*)d_in[5];
  const float* m1  = (const float*)d_in[6];
  const float* v1  = (const float*)d_in[7];
  const float* Wt2 = (const float*)d_in[8];
  const float* a12 = (const float*)d_in[9];
  const float* a22 = (const float*)d_in[10];
  const float* g2  = (const float*)d_in[11];
  const float* b2  = (const float*)d_in[12];
  const float* m2  = (const float*)d_in[13];
  const float* v2  = (const float*)d_in[14];
  const float* Wl  = (const float*)d_in[15];
  const float* bl  = (const float*)d_in[16];
  float* out = (float*)d_out;

  int B = in_sizes[0] / 1250;

  hipLaunchKernelGGL(gat_mfma, dim3(NBLKS), dim3(BSZ), 0, stream,
                     x, Wt1, a11, a21, g1, b1, m1, v1,
                     Wt2, a12, a22, g2, b2, m2, v2, Wl, bl, out, B);
}